// Round 3
// baseline (568.012 us; speedup 1.0000x reference)
//
#include <hip/hip_runtime.h>
#include <math.h>

#define N_ENTITY 64368
#define N_REL 12
#define DIM 128
#define NB 8
#define N_ITEM 6924
#define NEDGE 1000000
#define BATCH 128
#define SEQL 32
#define ITEM_TILE 32
#define CAP2 32   // src-bucket capacity; P(Poisson(1.67) >= 32) ~ 1e-26/src

// ---------------------------------------------------------------------------
// Phase 1: single pass over edges.  For each kept edge (dst < N_ITEM):
//   cursorD[d]++            (true in-degree, used by finalize)
//   bucketS[src] += (dst | type<<13)   (src-major work list, atomic cursor)
// dst < 6924 < 2^13, type < 12.
// ---------------------------------------------------------------------------
__global__ __launch_bounds__(256) void fill_kernel(
    const int* __restrict__ e_src, const int* __restrict__ e_dst,
    const int* __restrict__ e_type, int* __restrict__ cursorD,
    int* __restrict__ cursorS, int* __restrict__ bucketS)
{
    int gid = blockIdx.x * 256 + threadIdx.x;
    if (gid * 4 >= NEDGE) return;
    int4 s4 = reinterpret_cast<const int4*>(e_src)[gid];
    int4 d4 = reinterpret_cast<const int4*>(e_dst)[gid];
    int4 t4 = reinterpret_cast<const int4*>(e_type)[gid];

    #pragma unroll
    for (int k = 0; k < 4; ++k) {
        int s = (k == 0) ? s4.x : (k == 1) ? s4.y : (k == 2) ? s4.z : s4.w;
        int d = (k == 0) ? d4.x : (k == 1) ? d4.y : (k == 2) ? d4.z : d4.w;
        int t = (k == 0) ? t4.x : (k == 1) ? t4.y : (k == 2) ? t4.z : t4.w;
        if (d < N_ITEM) {
            atomicAdd(&cursorD[d], 1);
            int p2 = atomicAdd(&cursorS[s], 1);
            if (p2 < CAP2) bucketS[s * CAP2 + p2] = d | (t << 13);
        }
    }
}

// ---------------------------------------------------------------------------
// Phase 2 (src-major): one 32-lane half-wave per src.  Blocks cover srcs
// sequentially, so the 8 basis planes are read as 8 near-sequential streams
// (streaming HBM BW, one 4KB slab per DISTINCT src: 214MB not 440MB).
// Per incident edge: 32 FMA/lane-group + 4 hardware f32 atomic adds into the
// 3.5MB L2-resident accumulator.  No message materialization.
// ---------------------------------------------------------------------------
__global__ __launch_bounds__(256) void accum_kernel(
    const int* __restrict__ cursorS, const int* __restrict__ bucketS,
    const float* __restrict__ basis, const float* __restrict__ att,
    float* __restrict__ acc)
{
    __shared__ float att_s[N_REL * NB];
    if (threadIdx.x < N_REL * NB) att_s[threadIdx.x] = att[threadIdx.x];
    __syncthreads();

    int wave = threadIdx.x >> 6;
    int lane = threadIdx.x & 63;
    int half = lane >> 5;
    int l32  = lane & 31;                 // covers dims 4*l32 .. 4*l32+3
    int s    = blockIdx.x * 8 + wave * 2 + half;
    if (s >= N_ENTITY) return;

    int n = cursorS[s];
    if (n <= 0) return;
    if (n > CAP2) n = CAP2;

    // slab load: 8 planes x float4 per lane (512B per plane per half-wave)
    float4 v[NB];
    const float* bp = basis + (size_t)s * DIM + (l32 << 2);
    #pragma unroll
    for (int b = 0; b < NB; ++b)
        v[b] = *reinterpret_cast<const float4*>(bp + (size_t)b * (N_ENTITY * DIM));

    int pk = 0;
    if (l32 < n) pk = bucketS[s * CAP2 + l32];

    for (int j = 0; j < n; ++j) {
        // source lane is inside this half and active for all j < n
        int p = __shfl(pk, (half << 5) + j);
        int d = p & 0x1FFF;
        int t = p >> 13;
        float4 m = make_float4(0.f, 0.f, 0.f, 0.f);
        #pragma unroll
        for (int b = 0; b < NB; ++b) {
            float a = att_s[t * NB + b];
            m.x += a * v[b].x;
            m.y += a * v[b].y;
            m.z += a * v[b].z;
            m.w += a * v[b].w;
        }
        float* dst = acc + (size_t)d * DIM + (l32 << 2);
        unsafeAtomicAdd(dst + 0, m.x);
        unsafeAtomicAdd(dst + 1, m.y);
        unsafeAtomicAdd(dst + 2, m.z);
        unsafeAtomicAdd(dst + 3, m.w);
    }
}

// ---------------------------------------------------------------------------
// Phase 3: finalize  nodes = acc/deg + root + bias   (10MB, trivially bound)
// ---------------------------------------------------------------------------
__global__ __launch_bounds__(256) void finalize_kernel(
    const int* __restrict__ cursorD, const float* __restrict__ acc,
    const float* __restrict__ root, const float* __restrict__ bias,
    float* __restrict__ nodes)
{
    int gid = blockIdx.x * 256 + threadIdx.x;          // float4 index
    if (gid >= N_ITEM * (DIM / 4)) return;
    int row = gid >> 5;
    int q   = gid & 31;
    float inv = 1.0f / fmaxf((float)cursorD[row], 1.0f);
    float4 a = reinterpret_cast<const float4*>(acc)[gid];
    float4 r = reinterpret_cast<const float4*>(root)[gid];
    float4 b = reinterpret_cast<const float4*>(bias)[q];
    float4 o;
    o.x = a.x * inv + r.x + b.x;
    o.y = a.y * inv + r.y + b.y;
    o.z = a.z * inv + r.z + b.z;
    o.w = a.w * inv + r.w + b.w;
    reinterpret_cast<float4*>(nodes)[gid] = o;
}

// ---------------------------------------------------------------------------
// Phase 4: attention pool.  One block per batch row.  (unchanged)
// ---------------------------------------------------------------------------
__global__ __launch_bounds__(256) void pool_kernel(
    const float* __restrict__ nodes, const int* __restrict__ seed_ids,
    const int* __restrict__ seed_len, const float* __restrict__ attn_a,
    const float* __restrict__ attn_b, float* __restrict__ u)
{
    __shared__ float h[SEQL * 132];
    __shared__ float ev[SEQL];
    __shared__ float attw[SEQL];
    __shared__ int   seeds[SEQL];

    int b   = blockIdx.x;
    int tid = threadIdx.x;
    int len = seed_len[b];

    if (tid < SEQL) seeds[tid] = seed_ids[b * SEQL + tid];
    __syncthreads();

    for (int idx = tid; idx < SEQL * (DIM / 4); idx += 256) {
        int l  = idx >> 5;
        int kq = idx & 31;
        float4 v = reinterpret_cast<const float4*>(nodes)[(size_t)seeds[l] * 32 + kq];
        *reinterpret_cast<float4*>(h + l * 132 + kq * 4) = v;
    }
    __syncthreads();

    {
        int l = tid >> 3;
        int j = tid & 7;
        float dot[16];
        #pragma unroll
        for (int i = 0; i < 16; ++i) dot[i] = 0.f;
        const float* hr = h + l * 132;
        for (int k = 0; k < DIM; ++k) {
            float hv = hr[k];
            const float4* ar = reinterpret_cast<const float4*>(attn_a + k * DIM + j * 16);
            float4 a0 = ar[0], a1 = ar[1], a2 = ar[2], a3 = ar[3];
            dot[0]  += hv * a0.x; dot[1]  += hv * a0.y; dot[2]  += hv * a0.z; dot[3]  += hv * a0.w;
            dot[4]  += hv * a1.x; dot[5]  += hv * a1.y; dot[6]  += hv * a1.z; dot[7]  += hv * a1.w;
            dot[8]  += hv * a2.x; dot[9]  += hv * a2.y; dot[10] += hv * a2.z; dot[11] += hv * a2.w;
            dot[12] += hv * a3.x; dot[13] += hv * a3.y; dot[14] += hv * a3.z; dot[15] += hv * a3.w;
        }
        float sum = 0.f;
        #pragma unroll
        for (int i = 0; i < 16; ++i) sum += tanhf(dot[i]) * attn_b[j * 16 + i];
        sum += __shfl_xor(sum, 1);
        sum += __shfl_xor(sum, 2);
        sum += __shfl_xor(sum, 4);
        if (j == 0) ev[l] = sum;
    }
    __syncthreads();

    if (tid < SEQL) {
        float val = (tid < len) ? ev[tid] : -3.0e38f;
        float m = val;
        #pragma unroll
        for (int off = 16; off > 0; off >>= 1) m = fmaxf(m, __shfl_xor(m, off));
        float p = (tid < len) ? expf(val - m) : 0.f;
        float ssum = p;
        #pragma unroll
        for (int off = 16; off > 0; off >>= 1) ssum += __shfl_xor(ssum, off);
        attw[tid] = (len > 0) ? p / ssum : 0.f;
    }
    __syncthreads();

    if (tid < DIM) {
        float acc = 0.f;
        #pragma unroll
        for (int l = 0; l < SEQL; ++l) acc += attw[l] * h[l * 132 + tid];
        u[(size_t)b * DIM + tid] = acc;
    }
}

// ---------------------------------------------------------------------------
// Phase 5: scores[b,i] = u[b,:] . nodes[i,:] + out_bias[i]  (unchanged)
// ---------------------------------------------------------------------------
__global__ __launch_bounds__(256) void score_kernel(
    const float* __restrict__ nodes, const float* __restrict__ u,
    const float* __restrict__ out_bias, float* __restrict__ out)
{
    __shared__ float us[BATCH * DIM];
    __shared__ float ns[ITEM_TILE * 132];
    int tid   = threadIdx.x;
    int item0 = blockIdx.x * ITEM_TILE;

    for (int idx = tid; idx < BATCH * (DIM / 4); idx += 256)
        reinterpret_cast<float4*>(us)[idx] = reinterpret_cast<const float4*>(u)[idx];

    for (int idx = tid; idx < ITEM_TILE * (DIM / 4); idx += 256) {
        int j  = idx >> 5;
        int kq = idx & 31;
        int item = item0 + j;
        float4 v = make_float4(0.f, 0.f, 0.f, 0.f);
        if (item < N_ITEM) v = reinterpret_cast<const float4*>(nodes)[(size_t)item * 32 + kq];
        *reinterpret_cast<float4*>(ns + j * 132 + kq * 4) = v;
    }
    __syncthreads();

    int jg = tid & 15;
    int bg = tid >> 4;
    float acc0[8], acc1[8];
    #pragma unroll
    for (int i = 0; i < 8; ++i) { acc0[i] = 0.f; acc1[i] = 0.f; }
    const float* n0p = ns + (jg * 2 + 0) * 132;
    const float* n1p = ns + (jg * 2 + 1) * 132;
    for (int k = 0; k < DIM; k += 4) {
        float4 n0 = *reinterpret_cast<const float4*>(n0p + k);
        float4 n1 = *reinterpret_cast<const float4*>(n1p + k);
        #pragma unroll
        for (int bb = 0; bb < 8; ++bb) {
            float4 uv = *reinterpret_cast<const float4*>(us + (bg * 8 + bb) * DIM + k);
            acc0[bb] += uv.x * n0.x + uv.y * n0.y + uv.z * n0.z + uv.w * n0.w;
            acc1[bb] += uv.x * n1.x + uv.y * n1.y + uv.z * n1.z + uv.w * n1.w;
        }
    }
    #pragma unroll
    for (int bb = 0; bb < 8; ++bb) {
        int bi  = bg * 8 + bb;
        int it0 = item0 + jg * 2;
        if (it0     < N_ITEM) out[(size_t)bi * N_ITEM + it0]     = acc0[bb] + out_bias[it0];
        if (it0 + 1 < N_ITEM) out[(size_t)bi * N_ITEM + it0 + 1] = acc1[bb] + out_bias[it0 + 1];
    }
}

extern "C" void kernel_launch(void* const* d_in, const int* in_sizes, int n_in,
                              void* d_out, int out_size, void* d_ws, size_t ws_size,
                              hipStream_t stream)
{
    const int*   e_src     = (const int*)d_in[0];          // edge_idx[0]
    const int*   e_dst     = e_src + NEDGE;                // edge_idx[1]
    const int*   e_type    = (const int*)d_in[1];
    const int*   seed_ids  = (const int*)d_in[2];
    const int*   seed_len  = (const int*)d_in[3];
    // d_in[4] = labels (unused by reference)
    const float* basis     = (const float*)d_in[5];
    const float* att       = (const float*)d_in[6];
    const float* root      = (const float*)d_in[7];
    const float* rgcn_bias = (const float*)d_in[8];
    const float* attn_a    = (const float*)d_in[9];
    const float* attn_b    = (const float*)d_in[10];
    const float* out_bias  = (const float*)d_in[11];
    float*       out       = (float*)d_out;

    // workspace layout (~16 MB):
    //   cursorD[6928] | cursorS[64384] | acc[6924*128] | bucketS[64368*CAP2]
    //   | nodes[6924*128] | u[128*128]
    // cursorD..acc are contiguous -> single memset (3.83 MB).
    int*   cursorD = (int*)d_ws;
    int*   cursorS = cursorD + 6928;
    float* acc     = (float*)(cursorS + 64384);
    int*   bucketS = (int*)(acc + (size_t)N_ITEM * DIM);
    float* nodes   = (float*)(bucketS + (size_t)N_ENTITY * CAP2);
    float* u       = nodes + (size_t)N_ITEM * DIM;

    hipMemsetAsync(cursorD, 0,
                   (6928 + 64384 + (size_t)N_ITEM * DIM) * sizeof(int), stream);

    fill_kernel<<<(NEDGE / 4 + 255) / 256, 256, 0, stream>>>(
        e_src, e_dst, e_type, cursorD, cursorS, bucketS);
    accum_kernel<<<(N_ENTITY + 7) / 8, 256, 0, stream>>>(
        cursorS, bucketS, basis, att, acc);
    finalize_kernel<<<(N_ITEM * (DIM / 4) + 255) / 256, 256, 0, stream>>>(
        cursorD, acc, root, rgcn_bias, nodes);
    pool_kernel<<<BATCH, 256, 0, stream>>>(
        nodes, seed_ids, seed_len, attn_a, attn_b, u);
    score_kernel<<<(N_ITEM + ITEM_TILE - 1) / ITEM_TILE, 256, 0, stream>>>(
        nodes, u, out_bias, out);
}

// Round 5
// 486.878 us; speedup vs baseline: 1.1666x; 1.1666x over previous
//
#include <hip/hip_runtime.h>
#include <math.h>

#define N_ENTITY 64368
#define N_REL 12
#define DIM 128
#define NB 8
#define N_ITEM 6924
#define NEDGE 1000000
#define BATCH 128
#define SEQL 32
#define ITEM_TILE 32
#define CAPD 48   // dst slots; lambda=15.5, fixed-data max in-deg ~32, P(>=48) ~ 2e-7
#define CAP2 32   // src work-list capacity; lambda=1.67, unreachable

// ---------------------------------------------------------------------------
// Phase 1: single pass over edges.  Each kept edge (dst < N_ITEM):
//   pD = cursorD[d]++  -> reserved message slot  slot = d*CAPD + pD
//   append (slot | type<<19) to src-major work list bucketS[s]
// slot < 6924*48 = 332352 < 2^19; type < 12 -> fits bits 19..22.
// cursorD ends holding the TRUE in-degree (used for mean-normalization).
// ---------------------------------------------------------------------------
__global__ __launch_bounds__(256) void fill_kernel(
    const int* __restrict__ e_src, const int* __restrict__ e_dst,
    const int* __restrict__ e_type, int* __restrict__ cursorD,
    int* __restrict__ cursorS, int* __restrict__ bucketS)
{
    int gid = blockIdx.x * 256 + threadIdx.x;
    if (gid * 4 >= NEDGE) return;
    int4 s4 = reinterpret_cast<const int4*>(e_src)[gid];
    int4 d4 = reinterpret_cast<const int4*>(e_dst)[gid];
    int4 t4 = reinterpret_cast<const int4*>(e_type)[gid];

    #pragma unroll
    for (int k = 0; k < 4; ++k) {
        int s = (k == 0) ? s4.x : (k == 1) ? s4.y : (k == 2) ? s4.z : s4.w;
        int d = (k == 0) ? d4.x : (k == 1) ? d4.y : (k == 2) ? d4.z : d4.w;
        int t = (k == 0) ? t4.x : (k == 1) ? t4.y : (k == 2) ? t4.z : t4.w;
        if (d < N_ITEM) {
            int pD = atomicAdd(&cursorD[d], 1);
            if (pD < CAPD) {
                int slot = d * CAPD + pD;
                int pS = atomicAdd(&cursorS[s], 1);
                if (pS < CAP2) bucketS[s * CAP2 + pS] = slot | (t << 19);
            }
        }
    }
}

// ---------------------------------------------------------------------------
// Phase 2 (src-major): one 32-lane half-wave per src.  The 8 basis planes of
// each DISTINCT src are read ONCE (float4/lane, 512B per plane) -> 214MB not
// 440MB.  Per incident edge: 32 FMA + one plain 512B store to the edge's
// pre-assigned slot.  Each slot written exactly once -> NO atomics.
// ---------------------------------------------------------------------------
__global__ __launch_bounds__(256) void msg_kernel(
    const int* __restrict__ cursorS, const int* __restrict__ bucketS,
    const float* __restrict__ basis, const float* __restrict__ att,
    float* __restrict__ msg)
{
    __shared__ float att_s[N_REL * NB];
    if (threadIdx.x < N_REL * NB) att_s[threadIdx.x] = att[threadIdx.x];
    __syncthreads();

    int wave = threadIdx.x >> 6;
    int lane = threadIdx.x & 63;
    int half = lane >> 5;
    int l32  = lane & 31;                 // covers dims 4*l32 .. 4*l32+3
    int s    = blockIdx.x * 8 + wave * 2 + half;
    if (s >= N_ENTITY) return;

    int n = cursorS[s];
    if (n <= 0) return;
    if (n > CAP2) n = CAP2;

    float4 v[NB];
    const float* bp = basis + (size_t)s * DIM + (l32 << 2);
    #pragma unroll
    for (int b = 0; b < NB; ++b)
        v[b] = *reinterpret_cast<const float4*>(bp + (size_t)b * (N_ENTITY * DIM));

    int pk = 0;
    if (l32 < n) pk = bucketS[s * CAP2 + l32];

    for (int j = 0; j < n; ++j) {
        int p    = __shfl(pk, (half << 5) + j);   // source lane inside this half
        int slot = p & 0x7FFFF;
        int t    = ((unsigned)p) >> 19;
        float4 m = make_float4(0.f, 0.f, 0.f, 0.f);
        #pragma unroll
        for (int b = 0; b < NB; ++b) {
            float a = att_s[t * NB + b];
            m.x += a * v[b].x;
            m.y += a * v[b].y;
            m.z += a * v[b].z;
            m.w += a * v[b].w;
        }
        *reinterpret_cast<float4*>(msg + (size_t)slot * DIM + (l32 << 2)) = m;
    }
}

// ---------------------------------------------------------------------------
// Phase 3 (dst-major): a dst's messages occupy the FIRST n slots of its
// stride region -> ~8KB sequential burst per dst, near-streaming DRAM
// efficiency.  One wave per row, halves take alternating messages.
// Fused epilogue: mean-normalize by TRUE degree + root + bias.
// ---------------------------------------------------------------------------
__global__ __launch_bounds__(256) void reduce_kernel(
    const int* __restrict__ cursorD, const float* __restrict__ msg,
    const float* __restrict__ root, const float* __restrict__ bias,
    float* __restrict__ nodes)
{
    int wave = threadIdx.x >> 6;
    int lane = threadIdx.x & 63;
    int half = lane >> 5;
    int l32  = lane & 31;
    int row  = blockIdx.x * 4 + wave;
    if (row >= N_ITEM) return;

    int deg = cursorD[row];
    int n   = (deg > CAPD) ? CAPD : deg;

    float4 acc = make_float4(0.f, 0.f, 0.f, 0.f);
    const float* mp = msg + (size_t)row * CAPD * DIM + (l32 << 2);
    for (int i = half; i < n; i += 2) {
        float4 m = *reinterpret_cast<const float4*>(mp + (size_t)i * DIM);
        acc.x += m.x; acc.y += m.y; acc.z += m.z; acc.w += m.w;
    }
    acc.x += __shfl_xor(acc.x, 32);
    acc.y += __shfl_xor(acc.y, 32);
    acc.z += __shfl_xor(acc.z, 32);
    acc.w += __shfl_xor(acc.w, 32);

    if (half == 0) {
        float  inv = 1.0f / fmaxf((float)deg, 1.0f);
        float4 r   = *reinterpret_cast<const float4*>(root + (size_t)row * DIM + (l32 << 2));
        float4 bs  = *reinterpret_cast<const float4*>(bias + (l32 << 2));
        float4 o;
        o.x = acc.x * inv + r.x + bs.x;
        o.y = acc.y * inv + r.y + bs.y;
        o.z = acc.z * inv + r.z + bs.z;
        o.w = acc.w * inv + r.w + bs.w;
        *reinterpret_cast<float4*>(nodes + (size_t)row * DIM + (l32 << 2)) = o;
    }
}

// ---------------------------------------------------------------------------
// Phase 4: attention pool.  One block per batch row.  (unchanged)
// ---------------------------------------------------------------------------
__global__ __launch_bounds__(256) void pool_kernel(
    const float* __restrict__ nodes, const int* __restrict__ seed_ids,
    const int* __restrict__ seed_len, const float* __restrict__ attn_a,
    const float* __restrict__ attn_b, float* __restrict__ u)
{
    __shared__ float h[SEQL * 132];
    __shared__ float ev[SEQL];
    __shared__ float attw[SEQL];
    __shared__ int   seeds[SEQL];

    int b   = blockIdx.x;
    int tid = threadIdx.x;
    int len = seed_len[b];

    if (tid < SEQL) seeds[tid] = seed_ids[b * SEQL + tid];
    __syncthreads();

    for (int idx = tid; idx < SEQL * (DIM / 4); idx += 256) {
        int l  = idx >> 5;
        int kq = idx & 31;
        float4 v = reinterpret_cast<const float4*>(nodes)[(size_t)seeds[l] * 32 + kq];
        *reinterpret_cast<float4*>(h + l * 132 + kq * 4) = v;
    }
    __syncthreads();

    {
        int l = tid >> 3;
        int j = tid & 7;
        float dot[16];
        #pragma unroll
        for (int i = 0; i < 16; ++i) dot[i] = 0.f;
        const float* hr = h + l * 132;
        for (int k = 0; k < DIM; ++k) {
            float hv = hr[k];
            const float4* ar = reinterpret_cast<const float4*>(attn_a + k * DIM + j * 16);
            float4 a0 = ar[0], a1 = ar[1], a2 = ar[2], a3 = ar[3];
            dot[0]  += hv * a0.x; dot[1]  += hv * a0.y; dot[2]  += hv * a0.z; dot[3]  += hv * a0.w;
            dot[4]  += hv * a1.x; dot[5]  += hv * a1.y; dot[6]  += hv * a1.z; dot[7]  += hv * a1.w;
            dot[8]  += hv * a2.x; dot[9]  += hv * a2.y; dot[10] += hv * a2.z; dot[11] += hv * a2.w;
            dot[12] += hv * a3.x; dot[13] += hv * a3.y; dot[14] += hv * a3.z; dot[15] += hv * a3.w;
        }
        float sum = 0.f;
        #pragma unroll
        for (int i = 0; i < 16; ++i) sum += tanhf(dot[i]) * attn_b[j * 16 + i];
        sum += __shfl_xor(sum, 1);
        sum += __shfl_xor(sum, 2);
        sum += __shfl_xor(sum, 4);
        if (j == 0) ev[l] = sum;
    }
    __syncthreads();

    if (tid < SEQL) {
        float val = (tid < len) ? ev[tid] : -3.0e38f;
        float m = val;
        #pragma unroll
        for (int off = 16; off > 0; off >>= 1) m = fmaxf(m, __shfl_xor(m, off));
        float p = (tid < len) ? expf(val - m) : 0.f;
        float ssum = p;
        #pragma unroll
        for (int off = 16; off > 0; off >>= 1) ssum += __shfl_xor(ssum, off);
        attw[tid] = (len > 0) ? p / ssum : 0.f;
    }
    __syncthreads();

    if (tid < DIM) {
        float acc = 0.f;
        #pragma unroll
        for (int l = 0; l < SEQL; ++l) acc += attw[l] * h[l * 132 + tid];
        u[(size_t)b * DIM + tid] = acc;
    }
}

// ---------------------------------------------------------------------------
// Phase 5: scores[b,i] = u[b,:] . nodes[i,:] + out_bias[i]  (unchanged)
// ---------------------------------------------------------------------------
__global__ __launch_bounds__(256) void score_kernel(
    const float* __restrict__ nodes, const float* __restrict__ u,
    const float* __restrict__ out_bias, float* __restrict__ out)
{
    __shared__ float us[BATCH * DIM];
    __shared__ float ns[ITEM_TILE * 132];
    int tid   = threadIdx.x;
    int item0 = blockIdx.x * ITEM_TILE;

    for (int idx = tid; idx < BATCH * (DIM / 4); idx += 256)
        reinterpret_cast<float4*>(us)[idx] = reinterpret_cast<const float4*>(u)[idx];

    for (int idx = tid; idx < ITEM_TILE * (DIM / 4); idx += 256) {
        int j  = idx >> 5;
        int kq = idx & 31;
        int item = item0 + j;
        float4 v = make_float4(0.f, 0.f, 0.f, 0.f);
        if (item < N_ITEM) v = reinterpret_cast<const float4*>(nodes)[(size_t)item * 32 + kq];
        *reinterpret_cast<float4*>(ns + j * 132 + kq * 4) = v;
    }
    __syncthreads();

    int jg = tid & 15;
    int bg = tid >> 4;
    float acc0[8], acc1[8];
    #pragma unroll
    for (int i = 0; i < 8; ++i) { acc0[i] = 0.f; acc1[i] = 0.f; }
    const float* n0p = ns + (jg * 2 + 0) * 132;
    const float* n1p = ns + (jg * 2 + 1) * 132;
    for (int k = 0; k < DIM; k += 4) {
        float4 n0 = *reinterpret_cast<const float4*>(n0p + k);
        float4 n1 = *reinterpret_cast<const float4*>(n1p + k);
        #pragma unroll
        for (int bb = 0; bb < 8; ++bb) {
            float4 uv = *reinterpret_cast<const float4*>(us + (bg * 8 + bb) * DIM + k);
            acc0[bb] += uv.x * n0.x + uv.y * n0.y + uv.z * n0.z + uv.w * n0.w;
            acc1[bb] += uv.x * n1.x + uv.y * n1.y + uv.z * n1.z + uv.w * n1.w;
        }
    }
    #pragma unroll
    for (int bb = 0; bb < 8; ++bb) {
        int bi  = bg * 8 + bb;
        int it0 = item0 + jg * 2;
        if (it0     < N_ITEM) out[(size_t)bi * N_ITEM + it0]     = acc0[bb] + out_bias[it0];
        if (it0 + 1 < N_ITEM) out[(size_t)bi * N_ITEM + it0 + 1] = acc1[bb] + out_bias[it0 + 1];
    }
}

extern "C" void kernel_launch(void* const* d_in, const int* in_sizes, int n_in,
                              void* d_out, int out_size, void* d_ws, size_t ws_size,
                              hipStream_t stream)
{
    const int*   e_src     = (const int*)d_in[0];          // edge_idx[0]
    const int*   e_dst     = e_src + NEDGE;                // edge_idx[1]
    const int*   e_type    = (const int*)d_in[1];
    const int*   seed_ids  = (const int*)d_in[2];
    const int*   seed_len  = (const int*)d_in[3];
    // d_in[4] = labels (unused by reference)
    const float* basis     = (const float*)d_in[5];
    const float* att       = (const float*)d_in[6];
    const float* root      = (const float*)d_in[7];
    const float* rgcn_bias = (const float*)d_in[8];
    const float* attn_a    = (const float*)d_in[9];
    const float* attn_b    = (const float*)d_in[10];
    const float* out_bias  = (const float*)d_in[11];
    float*       out       = (float*)d_out;

    // workspace layout (~182 MB):
    //   cursorD[6928] | cursorS[64384] | bucketS[64368*CAP2]
    //   | msg[6924*CAPD*128] | nodes[6924*128] | u[128*128]
    // only cursorD+cursorS need zeroing (285 KB, one memset).
    int*   cursorD = (int*)d_ws;
    int*   cursorS = cursorD + 6928;
    int*   bucketS = cursorS + 64384;
    float* msg     = (float*)(bucketS + (size_t)N_ENTITY * CAP2);
    float* nodes   = msg + (size_t)N_ITEM * CAPD * DIM;
    float* u       = nodes + (size_t)N_ITEM * DIM;

    hipMemsetAsync(cursorD, 0, (6928 + 64384) * sizeof(int), stream);

    fill_kernel<<<(NEDGE / 4 + 255) / 256, 256, 0, stream>>>(
        e_src, e_dst, e_type, cursorD, cursorS, bucketS);
    msg_kernel<<<(N_ENTITY + 7) / 8, 256, 0, stream>>>(
        cursorS, bucketS, basis, att, msg);
    reduce_kernel<<<(N_ITEM + 3) / 4, 256, 0, stream>>>(
        cursorD, msg, root, rgcn_bias, nodes);
    pool_kernel<<<BATCH, 256, 0, stream>>>(
        nodes, seed_ids, seed_len, attn_a, attn_b, u);
    score_kernel<<<(N_ITEM + ITEM_TILE - 1) / ITEM_TILE, 256, 0, stream>>>(
        nodes, u, out_bias, out);
}

// Round 6
// 464.518 us; speedup vs baseline: 1.2228x; 1.0481x over previous
//
#include <hip/hip_runtime.h>
#include <math.h>

#define N_ENTITY 64368
#define N_REL 12
#define DIM 128
#define NB 8
#define N_ITEM 6924
#define NEDGE 1000000
#define BATCH 128
#define SEQL 32
#define ITEM_TILE 32
#define CAP 96   // fixed bucket capacity per dst; P(Poisson(15.5) >= 96) < 1e-40

// ---------------------------------------------------------------------------
// Phase 1: single-pass bucketing.  Fixed-stride CAP-slot buckets per dst with
// atomic cursors.  int4-vectorized edge reads.  cursor[d] ends holding the
// TRUE degree (uncapped); stores are clamped.
// Measured verdicts (R2/R3/R5): src-major message round-trips and fp32
// atomics both LOSE to this direct dst-major structure -- L3 (256MB) already
// dedups repeated src-slab reads during the aggregate window.
// ---------------------------------------------------------------------------
__global__ __launch_bounds__(256) void fill_kernel(
    const int* __restrict__ e_src, const int* __restrict__ e_dst,
    const int* __restrict__ e_type, int* __restrict__ cursor,
    int* __restrict__ bucket)
{
    int gid = blockIdx.x * 256 + threadIdx.x;
    if (gid * 4 >= NEDGE) return;
    int4 s4 = reinterpret_cast<const int4*>(e_src)[gid];
    int4 d4 = reinterpret_cast<const int4*>(e_dst)[gid];
    int4 t4 = reinterpret_cast<const int4*>(e_type)[gid];

    #pragma unroll
    for (int k = 0; k < 4; ++k) {
        int s = (k == 0) ? s4.x : (k == 1) ? s4.y : (k == 2) ? s4.z : s4.w;
        int d = (k == 0) ? d4.x : (k == 1) ? d4.y : (k == 2) ? d4.z : d4.w;
        int t = (k == 0) ? t4.x : (k == 1) ? t4.y : (k == 2) ? t4.z : t4.w;
        if (d < N_ITEM) {
            int pos = atomicAdd(&cursor[d], 1);
            if (pos < CAP) bucket[d * CAP + pos] = s | (t << 17);
        }
    }
}

// ---------------------------------------------------------------------------
// Phase 2: one wave per item row, split into two 32-lane halves that each
// process a DIFFERENT edge per iteration with float4 gathers (16B/lane).
// Per edge: 8 basis-plane reads (512B coalesced each) + 32 FMA/lane.
// Halves summed with shfl_xor(32); fused epilogue (mean-normalize by TRUE
// degree + root + bias).  No fp32 atomics anywhere.
// ---------------------------------------------------------------------------
__global__ __launch_bounds__(256) void aggregate_kernel(
    const int* __restrict__ cursor, const int* __restrict__ bucket,
    const float* __restrict__ basis, const float* __restrict__ att,
    const float* __restrict__ root, const float* __restrict__ bias,
    float* __restrict__ nodes)
{
    __shared__ float att_s[N_REL * NB];
    if (threadIdx.x < N_REL * NB) att_s[threadIdx.x] = att[threadIdx.x];
    __syncthreads();

    int wave = threadIdx.x >> 6;
    int lane = threadIdx.x & 63;
    int half = lane >> 5;      // 0 or 1: which edge of the pair
    int l32  = lane & 31;      // covers dims 4*l32 .. 4*l32+3
    int row  = blockIdx.x * 4 + wave;
    if (row >= N_ITEM) return;

    int deg = cursor[row];               // true degree
    int n   = (deg > CAP) ? CAP : deg;   // edges actually stored

    float4 acc = make_float4(0.f, 0.f, 0.f, 0.f);
    const int* bkt = bucket + (size_t)row * CAP;

    for (int base = 0; base < n; base += 64) {
        int m = n - base; if (m > 64) m = 64;
        int pk = 0;
        if (lane < m) pk = bkt[base + lane];
        for (int j = 0; j < m; j += 2) {
            int e     = j + half;
            int esafe = (e < m) ? e : 0;
            int p     = __shfl(pk, esafe);      // all lanes active in shfl
            if (e < m) {
                int ss = p & 0x1FFFF;
                int tt = p >> 17;
                const float* bp = basis + (size_t)ss * DIM + (l32 << 2);
                #pragma unroll
                for (int b = 0; b < NB; ++b) {
                    float  a = att_s[tt * NB + b];
                    float4 v = *reinterpret_cast<const float4*>(
                                   bp + (size_t)b * (N_ENTITY * DIM));
                    acc.x += a * v.x;
                    acc.y += a * v.y;
                    acc.z += a * v.z;
                    acc.w += a * v.w;
                }
            }
        }
    }

    // combine the two half-wave partial sums (same dims, different edges)
    acc.x += __shfl_xor(acc.x, 32);
    acc.y += __shfl_xor(acc.y, 32);
    acc.z += __shfl_xor(acc.z, 32);
    acc.w += __shfl_xor(acc.w, 32);

    if (half == 0) {
        float  inv = 1.0f / fmaxf((float)deg, 1.0f);
        float4 r   = *reinterpret_cast<const float4*>(root + (size_t)row * DIM + (l32 << 2));
        float4 bs  = *reinterpret_cast<const float4*>(bias + (l32 << 2));
        float4 o;
        o.x = acc.x * inv + r.x + bs.x;
        o.y = acc.y * inv + r.y + bs.y;
        o.z = acc.z * inv + r.z + bs.z;
        o.w = acc.w * inv + r.w + bs.w;
        *reinterpret_cast<float4*>(nodes + (size_t)row * DIM + (l32 << 2)) = o;
    }
}

// ---------------------------------------------------------------------------
// Phase 3: attention pool.  One block per batch row.
// ---------------------------------------------------------------------------
__global__ __launch_bounds__(256) void pool_kernel(
    const float* __restrict__ nodes, const int* __restrict__ seed_ids,
    const int* __restrict__ seed_len, const float* __restrict__ attn_a,
    const float* __restrict__ attn_b, float* __restrict__ u)
{
    __shared__ float h[SEQL * 132];
    __shared__ float ev[SEQL];
    __shared__ float attw[SEQL];
    __shared__ int   seeds[SEQL];

    int b   = blockIdx.x;
    int tid = threadIdx.x;
    int len = seed_len[b];

    if (tid < SEQL) seeds[tid] = seed_ids[b * SEQL + tid];
    __syncthreads();

    for (int idx = tid; idx < SEQL * (DIM / 4); idx += 256) {
        int l  = idx >> 5;
        int kq = idx & 31;
        float4 v = reinterpret_cast<const float4*>(nodes)[(size_t)seeds[l] * 32 + kq];
        *reinterpret_cast<float4*>(h + l * 132 + kq * 4) = v;
    }
    __syncthreads();

    {
        int l = tid >> 3;
        int j = tid & 7;
        float dot[16];
        #pragma unroll
        for (int i = 0; i < 16; ++i) dot[i] = 0.f;
        const float* hr = h + l * 132;
        for (int k = 0; k < DIM; ++k) {
            float hv = hr[k];
            const float4* ar = reinterpret_cast<const float4*>(attn_a + k * DIM + j * 16);
            float4 a0 = ar[0], a1 = ar[1], a2 = ar[2], a3 = ar[3];
            dot[0]  += hv * a0.x; dot[1]  += hv * a0.y; dot[2]  += hv * a0.z; dot[3]  += hv * a0.w;
            dot[4]  += hv * a1.x; dot[5]  += hv * a1.y; dot[6]  += hv * a1.z; dot[7]  += hv * a1.w;
            dot[8]  += hv * a2.x; dot[9]  += hv * a2.y; dot[10] += hv * a2.z; dot[11] += hv * a2.w;
            dot[12] += hv * a3.x; dot[13] += hv * a3.y; dot[14] += hv * a3.z; dot[15] += hv * a3.w;
        }
        float sum = 0.f;
        #pragma unroll
        for (int i = 0; i < 16; ++i) sum += tanhf(dot[i]) * attn_b[j * 16 + i];
        sum += __shfl_xor(sum, 1);
        sum += __shfl_xor(sum, 2);
        sum += __shfl_xor(sum, 4);
        if (j == 0) ev[l] = sum;
    }
    __syncthreads();

    if (tid < SEQL) {
        float val = (tid < len) ? ev[tid] : -3.0e38f;
        float m = val;
        #pragma unroll
        for (int off = 16; off > 0; off >>= 1) m = fmaxf(m, __shfl_xor(m, off));
        float p = (tid < len) ? expf(val - m) : 0.f;
        float ssum = p;
        #pragma unroll
        for (int off = 16; off > 0; off >>= 1) ssum += __shfl_xor(ssum, off);
        attw[tid] = (len > 0) ? p / ssum : 0.f;
    }
    __syncthreads();

    if (tid < DIM) {
        float acc = 0.f;
        #pragma unroll
        for (int l = 0; l < SEQL; ++l) acc += attw[l] * h[l * 132 + tid];
        u[(size_t)b * DIM + tid] = acc;
    }
}

// ---------------------------------------------------------------------------
// Phase 4: scores[b,i] = u[b,:] . nodes[i,:] + out_bias[i]
// ---------------------------------------------------------------------------
__global__ __launch_bounds__(256) void score_kernel(
    const float* __restrict__ nodes, const float* __restrict__ u,
    const float* __restrict__ out_bias, float* __restrict__ out)
{
    __shared__ float us[BATCH * DIM];
    __shared__ float ns[ITEM_TILE * 132];
    int tid   = threadIdx.x;
    int item0 = blockIdx.x * ITEM_TILE;

    for (int idx = tid; idx < BATCH * (DIM / 4); idx += 256)
        reinterpret_cast<float4*>(us)[idx] = reinterpret_cast<const float4*>(u)[idx];

    for (int idx = tid; idx < ITEM_TILE * (DIM / 4); idx += 256) {
        int j  = idx >> 5;
        int kq = idx & 31;
        int item = item0 + j;
        float4 v = make_float4(0.f, 0.f, 0.f, 0.f);
        if (item < N_ITEM) v = reinterpret_cast<const float4*>(nodes)[(size_t)item * 32 + kq];
        *reinterpret_cast<float4*>(ns + j * 132 + kq * 4) = v;
    }
    __syncthreads();

    int jg = tid & 15;
    int bg = tid >> 4;
    float acc0[8], acc1[8];
    #pragma unroll
    for (int i = 0; i < 8; ++i) { acc0[i] = 0.f; acc1[i] = 0.f; }
    const float* n0p = ns + (jg * 2 + 0) * 132;
    const float* n1p = ns + (jg * 2 + 1) * 132;
    for (int k = 0; k < DIM; k += 4) {
        float4 n0 = *reinterpret_cast<const float4*>(n0p + k);
        float4 n1 = *reinterpret_cast<const float4*>(n1p + k);
        #pragma unroll
        for (int bb = 0; bb < 8; ++bb) {
            float4 uv = *reinterpret_cast<const float4*>(us + (bg * 8 + bb) * DIM + k);
            acc0[bb] += uv.x * n0.x + uv.y * n0.y + uv.z * n0.z + uv.w * n0.w;
            acc1[bb] += uv.x * n1.x + uv.y * n1.y + uv.z * n1.z + uv.w * n1.w;
        }
    }
    #pragma unroll
    for (int bb = 0; bb < 8; ++bb) {
        int bi  = bg * 8 + bb;
        int it0 = item0 + jg * 2;
        if (it0     < N_ITEM) out[(size_t)bi * N_ITEM + it0]     = acc0[bb] + out_bias[it0];
        if (it0 + 1 < N_ITEM) out[(size_t)bi * N_ITEM + it0 + 1] = acc1[bb] + out_bias[it0 + 1];
    }
}

extern "C" void kernel_launch(void* const* d_in, const int* in_sizes, int n_in,
                              void* d_out, int out_size, void* d_ws, size_t ws_size,
                              hipStream_t stream)
{
    const int*   e_src     = (const int*)d_in[0];          // edge_idx[0]
    const int*   e_dst     = e_src + NEDGE;                // edge_idx[1]
    const int*   e_type    = (const int*)d_in[1];
    const int*   seed_ids  = (const int*)d_in[2];
    const int*   seed_len  = (const int*)d_in[3];
    // d_in[4] = labels (unused by reference)
    const float* basis     = (const float*)d_in[5];
    const float* att       = (const float*)d_in[6];
    const float* root      = (const float*)d_in[7];
    const float* rgcn_bias = (const float*)d_in[8];
    const float* attn_a    = (const float*)d_in[9];
    const float* attn_b    = (const float*)d_in[10];
    const float* out_bias  = (const float*)d_in[11];
    float*       out       = (float*)d_out;

    // workspace layout: cursor | bucket | nodes | u   (~6.3 MB)
    int*   cursor = (int*)d_ws;
    int*   bucket = cursor + 6928;
    float* nodes  = (float*)(bucket + (size_t)N_ITEM * CAP);
    float* u      = nodes + (size_t)N_ITEM * DIM;

    hipMemsetAsync(cursor, 0, 6928 * sizeof(int), stream);

    fill_kernel<<<(NEDGE / 4 + 255) / 256, 256, 0, stream>>>(
        e_src, e_dst, e_type, cursor, bucket);
    aggregate_kernel<<<(N_ITEM + 3) / 4, 256, 0, stream>>>(
        cursor, bucket, basis, att, root, rgcn_bias, nodes);
    pool_kernel<<<BATCH, 256, 0, stream>>>(
        nodes, seed_ids, seed_len, attn_a, attn_b, u);
    score_kernel<<<(N_ITEM + ITEM_TILE - 1) / ITEM_TILE, 256, 0, stream>>>(
        nodes, u, out_bias, out);
}